// Round 15
// baseline (237.245 us; speedup 1.0000x reference)
//
#include <hip/hip_runtime.h>

// GCN encoder, N=50000, E=800000.
// R15: k-sliced gather working set. R14's gemm1_fused showed FETCH=72.5MB for
// ~25MB of inputs: xb (9.6MB) > 4MB per-XCD L2 -> ~60% of random row gathers
// miss to L3 (latency-bound). Fix: store gathered features as 32-dim k-slices
// (3.2MB arrays, 64B rows) and gather in sequential passes, one L2-RESIDENT
// array per pass (read-only -> replicates in every XCD L2 harmlessly).
// K-slices align exactly with MFMA A-fragments (k=c*32+quad*8), so GEMMs read
// the sliced arrays at zero cost. Gathers de-fused (full occupancy, tiny).
// Pipeline: setup | place(1-pass fixed-stride CSR) | gather1(x3 passes in one
// grid) | gemm1 | gemm2 | gather2(x2) | gemm3.

#define N_NODES 50000
#define F_IN    96
#define HIDDEN  128
#define OUT_F   64
#define DCAP    64          // per-node csr capacity (ints)

typedef __attribute__((ext_vector_type(8))) short short8;
typedef __attribute__((ext_vector_type(4))) float floatx4;

__device__ inline unsigned short f2bf(float f) {          // RNE f32->bf16
    union { float f; unsigned u; } v; v.f = f;
    unsigned r = v.u + 0x7FFF + ((v.u >> 16) & 1);
    return (unsigned short)(r >> 16);
}
__device__ inline float bf2f(unsigned short b) {
    union { unsigned u; float f; } v; v.u = ((unsigned)b) << 16;
    return v.f;
}

// ---------------- setup: convert x into 3 k-sliced bf16 arrays + weights -----
__global__ __launch_bounds__(256) void setup_kernel(
    const float* __restrict__ x,
    const float* __restrict__ W1_rel, const float* __restrict__ W1_root,
    const float* __restrict__ W2_rel, const float* __restrict__ W2_root,
    unsigned short* __restrict__ xs0, unsigned short* __restrict__ xs1,
    unsigned short* __restrict__ xs2, unsigned short* __restrict__ W1b,
    unsigned short* __restrict__ W2rb, unsigned short* __restrict__ W2sb,
    int* __restrict__ degz, int total8, int nzero)
{
    int i = blockIdx.x * 256 + threadIdx.x;
    if (i < total8) {                         // i = (node, q) q in [0,12)
        int node = i / 12, q = i % 12;
        const float4* p = (const float4*)(x + (size_t)node * 96 + q * 8);
        float4 v0 = p[0], v1 = p[1];
        short8 o;
        o[0] = (short)f2bf(v0.x); o[1] = (short)f2bf(v0.y);
        o[2] = (short)f2bf(v0.z); o[3] = (short)f2bf(v0.w);
        o[4] = (short)f2bf(v1.x); o[5] = (short)f2bf(v1.y);
        o[6] = (short)f2bf(v1.z); o[7] = (short)f2bf(v1.w);
        unsigned short* arr = (q < 4) ? xs0 : (q < 8) ? xs1 : xs2;
        *(short8*)(arr + (size_t)node * 32 + (q & 3) * 8) = o;
    }
    if (i < nzero) degz[i] = 0;
    if (i < 128 * 192) {
        int j = i / 192, k = i % 192;
        float v = (k < 96) ? W1_rel[j * 96 + k] : W1_root[j * 96 + k - 96];
        W1b[i] = f2bf(v);
    } else if (i < 128 * 192 + 64 * 128) {
        int i2 = i - 128 * 192;
        W2rb[i2] = f2bf(W2_rel[i2]);
    } else if (i < 128 * 192 + 2 * 64 * 128) {
        int i3 = i - 128 * 192 - 64 * 128;
        W2sb[i3] = f2bf(W2_root[i3]);
    }
}

// ---------------- single-pass CSR: deg count + placement ---------------------
// blockIdx%8 -> dst slice (~XCD): deg atomics and csr writes stay XCD-local.
__global__ __launch_bounds__(256) void place_kernel(
    const int* __restrict__ ei, int* __restrict__ deg,
    int* __restrict__ csr, int E, int slice_size)
{
    int sl = blockIdx.x & 7;
    int i4 = (blockIdx.x >> 3) * 256 + threadIdx.x;
    int E4 = E >> 2;
    if (i4 < E4) {
        int4 d4 = ((const int4*)(ei + E))[i4];
        int e0 = i4 * 4;
        int dd[4] = {d4.x, d4.y, d4.z, d4.w};
        #pragma unroll
        for (int k = 0; k < 4; ++k) {
            int d = dd[k];
            if ((unsigned)d >= (unsigned)N_NODES) continue;
            if (d / slice_size != sl) continue;
            int s = ei[e0 + k];
            if (s == d) continue;             // remove_self_loops
            int r = atomicAdd(&deg[d], 1);
            if (r < DCAP) csr[d * DCAP + r] = s;
        }
    } else if (i4 == E4) {
        for (int e = E4 * 4; e < E; ++e) {
            int d = ei[E + e];
            if ((unsigned)d >= (unsigned)N_NODES) continue;
            if (d / slice_size != sl) continue;
            int s = ei[e];
            if (s == d) continue;
            int r = atomicAdd(&deg[d], 1);
            if (r < DCAP) csr[d * DCAP + r] = s;
        }
    }
}

// ---------------- k-sliced gather: one pass = one 3.2MB L2-resident array ----
// grid = tilesPP * npass; pass = blockIdx / tilesPP (runs roughly in order).
// 4 threads per node (one 16B feature chunk each); 64 nodes per block.
__global__ __launch_bounds__(256) void gather_ksliced(
    const unsigned short* __restrict__ f0, const unsigned short* __restrict__ f1,
    const unsigned short* __restrict__ f2,
    unsigned short* __restrict__ a0, unsigned short* __restrict__ a1,
    unsigned short* __restrict__ a2,
    const int* __restrict__ deg, const int* __restrict__ csr,
    int N, int tilesPP)
{
    const int pass = blockIdx.x / tilesPP;
    const unsigned short* __restrict__ F = (pass == 0) ? f0 : (pass == 1) ? f1 : f2;
    unsigned short* __restrict__ A = (pass == 0) ? a0 : (pass == 1) ? a1 : a2;
    const int tid = threadIdx.x;
    const int node = (blockIdx.x % tilesPP) * 64 + (tid >> 2);
    const int cq = tid & 3;
    if (node >= N) return;
    int dg = deg[node];
    if (dg > DCAP) dg = DCAP;
    int j = node * DCAP, end = j + dg;
    float acc[8] = {};
    const unsigned short* fc = F + cq * 8;
    for (; j + 3 < end; j += 4) {             // 4 independent 16B row loads
        int s0 = csr[j], s1 = csr[j + 1], s2 = csr[j + 2], s3 = csr[j + 3];
        s0 = ((unsigned)s0 < (unsigned)N_NODES) ? s0 : 0;
        s1 = ((unsigned)s1 < (unsigned)N_NODES) ? s1 : 0;
        s2 = ((unsigned)s2 < (unsigned)N_NODES) ? s2 : 0;
        s3 = ((unsigned)s3 < (unsigned)N_NODES) ? s3 : 0;
        short8 v0 = *(const short8*)(fc + (size_t)s0 * 32);
        short8 v1 = *(const short8*)(fc + (size_t)s1 * 32);
        short8 v2 = *(const short8*)(fc + (size_t)s2 * 32);
        short8 v3 = *(const short8*)(fc + (size_t)s3 * 32);
        #pragma unroll
        for (int i = 0; i < 8; ++i)
            acc[i] += (bf2f((unsigned short)v0[i]) + bf2f((unsigned short)v1[i]))
                    + (bf2f((unsigned short)v2[i]) + bf2f((unsigned short)v3[i]));
    }
    for (; j < end; ++j) {
        int s0 = csr[j];
        s0 = ((unsigned)s0 < (unsigned)N_NODES) ? s0 : 0;
        short8 v0 = *(const short8*)(fc + (size_t)s0 * 32);
        #pragma unroll
        for (int i = 0; i < 8; ++i) acc[i] += bf2f((unsigned short)v0[i]);
    }
    short8 o;
    #pragma unroll
    for (int i = 0; i < 8; ++i) o[i] = (short)f2bf(acc[i]);
    *(short8*)(A + (size_t)node * 32 + cq * 8) = o;
}

// ---------------- gemm1: h = relu([agg1|x]@W1b^T + b1), A from k-slices ------
__global__ __launch_bounds__(256) void gemm1_kernel(
    const unsigned short* __restrict__ a0, const unsigned short* __restrict__ a1,
    const unsigned short* __restrict__ a2,
    const unsigned short* __restrict__ xs0, const unsigned short* __restrict__ xs1,
    const unsigned short* __restrict__ xs2,
    const unsigned short* __restrict__ W1b, const float* __restrict__ b1,
    unsigned short* __restrict__ h, int N)
{
    const int lane = threadIdx.x & 63;
    const int wave = threadIdx.x >> 6;
    const int node_base = blockIdx.x * 64 + wave * 16;
    const int m = lane & 15, quad = lane >> 4;
    int na = node_base + m;
    if (na >= N) na = N - 1;                  // clamp (junk rows never stored)
    const size_t ro = (size_t)na * 32 + quad * 8;
    short8 a[6];
    a[0] = *(const short8*)(a0 + ro);
    a[1] = *(const short8*)(a1 + ro);
    a[2] = *(const short8*)(a2 + ro);
    a[3] = *(const short8*)(xs0 + ro);
    a[4] = *(const short8*)(xs1 + ro);
    a[5] = *(const short8*)(xs2 + ro);
    #pragma unroll
    for (int jt = 0; jt < 8; ++jt) {
        floatx4 acc = {0.f, 0.f, 0.f, 0.f};
        const unsigned short* wb = W1b + (size_t)(jt * 16 + m) * 192 + quad * 8;
        #pragma unroll
        for (int c = 0; c < 6; ++c) {
            short8 b = *(const short8*)(wb + c * 32);
            acc = __builtin_amdgcn_mfma_f32_16x16x32_bf16(a[c], b, acc, 0, 0, 0);
        }
        int col = jt * 16 + m;
        float bv = b1[col];
        #pragma unroll
        for (int r = 0; r < 4; ++r) {
            int node = node_base + quad * 4 + r;
            if (node < N)
                h[(size_t)node * 128 + col] = f2bf(fmaxf(acc[r] + bv, 0.f));
        }
    }
}

// ---------------- gemm2: t = h@W2rb^T, t stored k-sliced ---------------------
__global__ __launch_bounds__(256) void gemm2_kernel(
    const unsigned short* __restrict__ h, const unsigned short* __restrict__ W2rb,
    unsigned short* __restrict__ t0, unsigned short* __restrict__ t1, int N)
{
    const int lane = threadIdx.x & 63;
    const int wave = threadIdx.x >> 6;
    const int node_base = blockIdx.x * 64 + wave * 16;
    const int m = lane & 15, quad = lane >> 4;
    int na = node_base + m;
    if (na >= N) na = N - 1;
    short8 a[4];
    #pragma unroll
    for (int c = 0; c < 4; ++c)
        a[c] = *(const short8*)(h + (size_t)na * 128 + c * 32 + quad * 8);
    #pragma unroll
    for (int jt = 0; jt < 4; ++jt) {
        floatx4 acc = {0.f, 0.f, 0.f, 0.f};
        const unsigned short* wb = W2rb + (size_t)(jt * 16 + m) * 128 + quad * 8;
        #pragma unroll
        for (int c = 0; c < 4; ++c) {
            short8 b = *(const short8*)(wb + c * 32);
            acc = __builtin_amdgcn_mfma_f32_16x16x32_bf16(a[c], b, acc, 0, 0, 0);
        }
        int col = jt * 16 + m;
        unsigned short* tarr = (col < 32) ? t0 : t1;
        int co = col & 31;
        #pragma unroll
        for (int r = 0; r < 4; ++r) {
            int node = node_base + quad * 4 + r;
            if (node < N)
                tarr[(size_t)node * 32 + co] = f2bf(acc[r]);
        }
    }
}

// ---------------- gemm3: out = h@W2sb^T + b2 + agg2 (k-sliced addend) --------
__global__ __launch_bounds__(256) void gemm3_kernel(
    const unsigned short* __restrict__ h, const unsigned short* __restrict__ W2sb,
    const float* __restrict__ b2,
    const unsigned short* __restrict__ g0, const unsigned short* __restrict__ g1,
    float* __restrict__ out, int N)
{
    const int lane = threadIdx.x & 63;
    const int wave = threadIdx.x >> 6;
    const int node_base = blockIdx.x * 64 + wave * 16;
    const int m = lane & 15, quad = lane >> 4;
    int na = node_base + m;
    if (na >= N) na = N - 1;
    short8 a[4];
    #pragma unroll
    for (int c = 0; c < 4; ++c)
        a[c] = *(const short8*)(h + (size_t)na * 128 + c * 32 + quad * 8);
    #pragma unroll
    for (int jt = 0; jt < 4; ++jt) {
        floatx4 acc = {0.f, 0.f, 0.f, 0.f};
        const unsigned short* wb = W2sb + (size_t)(jt * 16 + m) * 128 + quad * 8;
        #pragma unroll
        for (int c = 0; c < 4; ++c) {
            short8 b = *(const short8*)(wb + c * 32);
            acc = __builtin_amdgcn_mfma_f32_16x16x32_bf16(a[c], b, acc, 0, 0, 0);
        }
        int col = jt * 16 + m;
        float bv = b2[col];
        const unsigned short* garr = (col < 32) ? g0 : g1;
        int co = col & 31;
        #pragma unroll
        for (int r = 0; r < 4; ++r) {
            int node = node_base + quad * 4 + r;
            if (node < N) {
                float v = acc[r] + bv + bf2f(garr[(size_t)node * 32 + co]);
                out[(size_t)node * 64 + col] = v;
            }
        }
    }
}

extern "C" void kernel_launch(void* const* d_in, const int* in_sizes, int n_in,
                              void* d_out, int out_size, void* d_ws, size_t ws_size,
                              hipStream_t stream) {
    const float* x       = (const float*)d_in[0];
    const int*   ei      = (const int*)d_in[1];
    const float* W1_rel  = (const float*)d_in[2];
    const float* b1      = (const float*)d_in[3];
    const float* W1_root = (const float*)d_in[4];
    const float* W2_rel  = (const float*)d_in[5];
    const float* b2      = (const float*)d_in[6];
    const float* W2_root = (const float*)d_in[7];
    float* out = (float*)d_out;

    const int N = in_sizes[0] / F_IN;       // 50000
    const int E = in_sizes[1] / 2;          // 800000
    const int slice_size = ((N + 2047) / 2048) * 256;   // 6400

    const size_t SLICE = (size_t)N_NODES * 32 * 2;       // 3.2 MB per k-slice

    // Workspace (~54 MB):
    char* ws = (char*)d_ws;
    size_t p = 0;
    unsigned short* xs0  = (unsigned short*)(ws + p); p += SLICE;
    unsigned short* xs1  = (unsigned short*)(ws + p); p += SLICE;
    unsigned short* xs2  = (unsigned short*)(ws + p); p += SLICE;
    unsigned short* ag0  = (unsigned short*)(ws + p); p += SLICE;
    unsigned short* ag1  = (unsigned short*)(ws + p); p += SLICE;
    unsigned short* ag2  = (unsigned short*)(ws + p); p += SLICE;
    unsigned short* t0   = (unsigned short*)(ws + p); p += SLICE;
    unsigned short* t1   = (unsigned short*)(ws + p); p += SLICE;
    unsigned short* g0   = (unsigned short*)(ws + p); p += SLICE;
    unsigned short* g1   = (unsigned short*)(ws + p); p += SLICE;
    unsigned short* h    = (unsigned short*)(ws + p); p += (size_t)N_NODES * HIDDEN * 2;
    unsigned short* W1b  = (unsigned short*)(ws + p); p += (size_t)128 * 192 * 2;
    unsigned short* W2rb = (unsigned short*)(ws + p); p += (size_t)64 * 128 * 2;
    unsigned short* W2sb = (unsigned short*)(ws + p); p += (size_t)64 * 128 * 2;
    int* deg = (int*)(ws + p);  p += (size_t)N_NODES * 4;
    int* csr = (int*)(ws + p);  p += (size_t)N_NODES * DCAP * 4;   // 12.8 MB

    // ---- setup (convert k-sliced + zero deg) ----
    {
        int total8 = N * 12;
        setup_kernel<<<(total8 + 255) / 256, 256, 0, stream>>>(
            x, W1_rel, W1_root, W2_rel, W2_root,
            xs0, xs1, xs2, W1b, W2rb, W2sb, deg, total8, N);
    }
    // ---- single-pass CSR build ----
    {
        int E4 = E >> 2;
        int bps = (E4 + 1 + 255) / 256;
        place_kernel<<<bps * 8, 256, 0, stream>>>(ei, deg, csr, E, slice_size);
    }

    const int tiles64 = (N + 63) / 64;       // 782

    // ---- layer 1 ----
    gather_ksliced<<<tiles64 * 3, 256, 0, stream>>>(
        xs0, xs1, xs2, ag0, ag1, ag2, deg, csr, N, tiles64);
    gemm1_kernel<<<tiles64, 256, 0, stream>>>(
        ag0, ag1, ag2, xs0, xs1, xs2, W1b, b1, h, N);

    // ---- layer 2 ----
    gemm2_kernel<<<tiles64, 256, 0, stream>>>(h, W2rb, t0, t1, N);
    gather_ksliced<<<tiles64 * 2, 256, 0, stream>>>(
        t0, t1, nullptr, g0, g1, nullptr, deg, csr, N, tiles64);
    gemm3_kernel<<<tiles64, 256, 0, stream>>>(h, W2sb, b2, g0, g1, out, N);
}

// Round 16
// 198.591 us; speedup vs baseline: 1.1946x; 1.1946x over previous
//
#include <hip/hip_runtime.h>

// GCN encoder, N=50000, E=800000.
// R16: R14 base (best: 205us; k-slicing R15 regressed — passes overlap, no L2
// residency materializes). Pipeline compression, gather untouched (it sits at
// its ~3.3TB/s MSHR/latency plateau; FETCH 72.5MB = each XCD pulls xb ~once):
//  - setup + place fused into one grid-partitioned kernel (independent bufs);
//    deg zeroing via 200KB hipMemsetAsync.
//  - gemm2 fused into gemm1 via R11-P5's LDS C->A transpose (correctness
//    validated in R12; hs[32][136]=8.7KB, total LDS 15.4KB -> no occ cliff).
// 4 dispatches: memset | setup_place | mega1(gather1+gemm1+gemm2) |
// gemm3_fused(gather2+gemm3).

#define N_NODES 50000
#define F_IN    96
#define HIDDEN  128
#define OUT_F   64
#define DCAP    64          // per-node csr capacity (ints)

typedef __attribute__((ext_vector_type(8))) short short8;
typedef __attribute__((ext_vector_type(4))) float floatx4;

__device__ inline unsigned short f2bf(float f) {          // RNE f32->bf16
    union { float f; unsigned u; } v; v.f = f;
    unsigned r = v.u + 0x7FFF + ((v.u >> 16) & 1);
    return (unsigned short)(r >> 16);
}
__device__ inline float bf2f(unsigned short b) {
    union { unsigned u; float f; } v; v.u = ((unsigned)b) << 16;
    return v.f;
}

// ---------------- fused setup (converts) + place (1-pass CSR) ----------------
// blocks [0,SB): convert x/weights to bf16. blocks [SB,..): place edges into
// fixed-stride csr, slice-swizzled so deg atomics + csr writes stay XCD-local.
__global__ __launch_bounds__(256) void setup_place_kernel(
    const float* __restrict__ x,
    const float* __restrict__ W1_rel, const float* __restrict__ W1_root,
    const float* __restrict__ W2_rel, const float* __restrict__ W2_root,
    const int* __restrict__ ei,
    unsigned short* __restrict__ xb, unsigned short* __restrict__ W1b,
    unsigned short* __restrict__ W2rb, unsigned short* __restrict__ W2sb,
    int* __restrict__ deg, int* __restrict__ csr,
    int SB, int total8, int E, int slice_size)
{
    const int tid = threadIdx.x;
    if ((int)blockIdx.x < SB) {
        // ---- setup part ----
        int i = blockIdx.x * 256 + tid;
        if (i < total8) {
            const float4* p = (const float4*)(x + (size_t)i * 8);
            float4 v0 = p[0], v1 = p[1];
            short8 o;
            o[0] = (short)f2bf(v0.x); o[1] = (short)f2bf(v0.y);
            o[2] = (short)f2bf(v0.z); o[3] = (short)f2bf(v0.w);
            o[4] = (short)f2bf(v1.x); o[5] = (short)f2bf(v1.y);
            o[6] = (short)f2bf(v1.z); o[7] = (short)f2bf(v1.w);
            *(short8*)(xb + (size_t)i * 8) = o;
        }
        if (i < 128 * 192) {
            int j = i / 192, k = i % 192;
            float v = (k < 96) ? W1_rel[j * 96 + k] : W1_root[j * 96 + k - 96];
            W1b[i] = f2bf(v);
        } else if (i < 128 * 192 + 64 * 128) {
            int i2 = i - 128 * 192;
            W2rb[i2] = f2bf(W2_rel[i2]);
        } else if (i < 128 * 192 + 2 * 64 * 128) {
            int i3 = i - 128 * 192 - 64 * 128;
            W2sb[i3] = f2bf(W2_root[i3]);
        }
        return;
    }
    // ---- place part ----
    int pb = blockIdx.x - SB;
    int sl = pb & 7;
    int i4 = (pb >> 3) * 256 + tid;
    int E4 = E >> 2;
    if (i4 < E4) {
        int4 d4 = ((const int4*)(ei + E))[i4];
        int e0 = i4 * 4;
        int dd[4] = {d4.x, d4.y, d4.z, d4.w};
        #pragma unroll
        for (int k = 0; k < 4; ++k) {
            int d = dd[k];
            if ((unsigned)d >= (unsigned)N_NODES) continue;
            if (d / slice_size != sl) continue;
            int s = ei[e0 + k];
            if (s == d) continue;             // remove_self_loops
            int r = atomicAdd(&deg[d], 1);
            if (r < DCAP) csr[d * DCAP + r] = s;
        }
    } else if (i4 == E4) {
        for (int e = E4 * 4; e < E; ++e) {
            int d = ei[E + e];
            if ((unsigned)d >= (unsigned)N_NODES) continue;
            if (d / slice_size != sl) continue;
            int s = ei[e];
            if (s == d) continue;
            int r = atomicAdd(&deg[d], 1);
            if (r < DCAP) csr[d * DCAP + r] = s;
        }
    }
}

// ---------------- gather helper: one (node,chunk) segment sum ----------------
template<int F>
__device__ inline void gather_row8(const unsigned short* __restrict__ feat,
                                   const int* __restrict__ csr, int j, int end,
                                   float* acc)
{
    const unsigned short* fc = feat;
    for (; j + 3 < end; j += 4) {
        int s0 = csr[j], s1 = csr[j + 1], s2 = csr[j + 2], s3 = csr[j + 3];
        s0 = ((unsigned)s0 < (unsigned)N_NODES) ? s0 : 0;
        s1 = ((unsigned)s1 < (unsigned)N_NODES) ? s1 : 0;
        s2 = ((unsigned)s2 < (unsigned)N_NODES) ? s2 : 0;
        s3 = ((unsigned)s3 < (unsigned)N_NODES) ? s3 : 0;
        short8 v0 = *(const short8*)(fc + (size_t)s0 * F);
        short8 v1 = *(const short8*)(fc + (size_t)s1 * F);
        short8 v2 = *(const short8*)(fc + (size_t)s2 * F);
        short8 v3 = *(const short8*)(fc + (size_t)s3 * F);
        #pragma unroll
        for (int i = 0; i < 8; ++i)
            acc[i] += (bf2f((unsigned short)v0[i]) + bf2f((unsigned short)v1[i]))
                    + (bf2f((unsigned short)v2[i]) + bf2f((unsigned short)v3[i]));
    }
    for (; j < end; ++j) {
        int s0 = csr[j];
        s0 = ((unsigned)s0 < (unsigned)N_NODES) ? s0 : 0;
        short8 v0 = *(const short8*)(fc + (size_t)s0 * F);
        #pragma unroll
        for (int i = 0; i < 8; ++i) acc[i] += bf2f((unsigned short)v0[i]);
    }
}

// ---------------- mega1: gather1 (LDS) + gemm1 + gemm2 (LDS transpose) -------
// 32-node tile. Gather: 384 tasks. gemm1: wave w -> node half (w&1), jt range
// (w>>1)*4. h tile kept in hs (C->A transpose) for the fused t = h@W2rb^T.
__global__ __launch_bounds__(256) void mega1_kernel(
    const unsigned short* __restrict__ xb, const unsigned short* __restrict__ W1b,
    const unsigned short* __restrict__ W2rb, const float* __restrict__ b1,
    const int* __restrict__ deg, const int* __restrict__ csr,
    unsigned short* __restrict__ h, unsigned short* __restrict__ t, int N)
{
    __shared__ __align__(16) unsigned short aggs[32][104];   // 6.7 KB
    __shared__ __align__(16) unsigned short hs[32][136];     // 8.7 KB
    const int tid = threadIdx.x;
    const int node0 = blockIdx.x * 32;

    // gather phase: 32 nodes x 12 chunks = 384 tasks
    for (int task = tid; task < 384; task += 256) {
        int nl = task / 12, c = task % 12;
        int node = node0 + nl;
        float acc[8] = {};
        if (node < N) {
            int dg = deg[node];
            if (dg > DCAP) dg = DCAP;
            int j = node * DCAP;
            gather_row8<F_IN>(xb + c * 8, csr, j, j + dg, acc);
        }
        short8 o;
        #pragma unroll
        for (int i = 0; i < 8; ++i) o[i] = (short)f2bf(acc[i]);
        *(short8*)&aggs[nl][c * 8] = o;
    }
    __syncthreads();

    // gemm1 phase
    const int lane = tid & 63;
    const int wave = tid >> 6;
    const int m = lane & 15, quad = lane >> 4;
    const int nh = wave & 1;                  // node half
    const int node_base = node0 + nh * 16;
    const int jt0 = (wave >> 1) * 4;          // 4 jt tiles per wave
    int na = node_base + m;
    if (na >= N) na = N - 1;                  // clamp (junk rows never stored)
    short8 a[6];
    #pragma unroll
    for (int c = 0; c < 3; ++c)               // agg from LDS
        a[c] = *(const short8*)&aggs[nh * 16 + m][c * 32 + quad * 8];
    #pragma unroll
    for (int c = 0; c < 3; ++c)               // x from global
        a[3 + c] = *(const short8*)(xb + (size_t)na * 96 + c * 32 + quad * 8);
    #pragma unroll
    for (int jt = 0; jt < 4; ++jt) {
        floatx4 acc = {0.f, 0.f, 0.f, 0.f};
        const unsigned short* wb = W1b + (size_t)((jt0 + jt) * 16 + m) * 192 + quad * 8;
        #pragma unroll
        for (int c = 0; c < 6; ++c) {
            short8 b = *(const short8*)(wb + c * 32);
            acc = __builtin_amdgcn_mfma_f32_16x16x32_bf16(a[c], b, acc, 0, 0, 0);
        }
        int col = (jt0 + jt) * 16 + m;
        float bv = b1[col];
        #pragma unroll
        for (int r = 0; r < 4; ++r) {
            int node = node_base + quad * 4 + r;
            float v = fmaxf(acc[r] + bv, 0.f);
            unsigned short vb = f2bf(v);
            hs[nh * 16 + quad * 4 + r][col] = vb;   // C->A transpose staging
            if (node < N) h[(size_t)node * 128 + col] = vb;
        }
    }
    __syncthreads();

    // gemm2 phase: t = h@W2rb^T, A-frags of h from hs
    const int jtt0 = (wave >> 1) * 2;         // 2 jt tiles per wave
    short8 a2[4];
    #pragma unroll
    for (int c = 0; c < 4; ++c)
        a2[c] = *(const short8*)&hs[nh * 16 + m][c * 32 + quad * 8];
    #pragma unroll
    for (int jt = 0; jt < 2; ++jt) {
        floatx4 acc = {0.f, 0.f, 0.f, 0.f};
        const unsigned short* wb = W2rb + (size_t)((jtt0 + jt) * 16 + m) * 128 + quad * 8;
        #pragma unroll
        for (int c = 0; c < 4; ++c) {
            short8 b = *(const short8*)(wb + c * 32);
            acc = __builtin_amdgcn_mfma_f32_16x16x32_bf16(a2[c], b, acc, 0, 0, 0);
        }
        int col = (jtt0 + jt) * 16 + m;
        #pragma unroll
        for (int r = 0; r < 4; ++r) {
            int node = node_base + quad * 4 + r;
            if (node < N)
                t[(size_t)node * 64 + col] = f2bf(acc[r]);
        }
    }
}

// ---------------- gemm3 fused: gather2 (LDS) + out = h@W2sb^T+b2+agg2 --------
__global__ __launch_bounds__(256) void gemm3_fused(
    const unsigned short* __restrict__ h, const unsigned short* __restrict__ tfeat,
    const unsigned short* __restrict__ W2sb, const float* __restrict__ b2,
    const int* __restrict__ deg, const int* __restrict__ csr,
    float* __restrict__ out, int N)
{
    __shared__ __align__(16) unsigned short agg2s[32][72];   // 4.6 KB
    const int tid = threadIdx.x;
    const int node0 = blockIdx.x * 32;

    // gather phase: 32 nodes x 8 chunks = 256 tasks, 1 per thread
    {
        int nl = tid / 8, c = tid % 8;
        int node = node0 + nl;
        float acc[8] = {};
        if (node < N) {
            int dg = deg[node];
            if (dg > DCAP) dg = DCAP;
            int j = node * DCAP;
            gather_row8<OUT_F>(tfeat + c * 8, csr, j, j + dg, acc);
        }
        short8 o;
        #pragma unroll
        for (int i = 0; i < 8; ++i) o[i] = (short)f2bf(acc[i]);
        *(short8*)&agg2s[nl][c * 8] = o;
    }
    __syncthreads();

    // MFMA phase
    const int lane = tid & 63;
    const int wave = tid >> 6;
    const int m = lane & 15, quad = lane >> 4;
    const int node_base = node0 + (wave & 1) * 16;
    const int jt0 = (wave >> 1) * 2;          // 2 jt tiles per wave
    int na = node_base + m;
    if (na >= N) na = N - 1;
    short8 a[4];
    #pragma unroll
    for (int c = 0; c < 4; ++c)
        a[c] = *(const short8*)(h + (size_t)na * 128 + c * 32 + quad * 8);
    #pragma unroll
    for (int jt = 0; jt < 2; ++jt) {
        floatx4 acc = {0.f, 0.f, 0.f, 0.f};
        const unsigned short* wb = W2sb + (size_t)((jt0 + jt) * 16 + m) * 128 + quad * 8;
        #pragma unroll
        for (int c = 0; c < 4; ++c) {
            short8 b = *(const short8*)(wb + c * 32);
            acc = __builtin_amdgcn_mfma_f32_16x16x32_bf16(a[c], b, acc, 0, 0, 0);
        }
        int col = (jt0 + jt) * 16 + m;
        float bv = b2[col];
        #pragma unroll
        for (int r = 0; r < 4; ++r) {
            int node = node_base + quad * 4 + r;
            if (node < N) {
                int nl = (wave & 1) * 16 + quad * 4 + r;
                float v = acc[r] + bv + bf2f(agg2s[nl][col]);
                out[(size_t)node * 64 + col] = v;
            }
        }
    }
}

extern "C" void kernel_launch(void* const* d_in, const int* in_sizes, int n_in,
                              void* d_out, int out_size, void* d_ws, size_t ws_size,
                              hipStream_t stream) {
    const float* x       = (const float*)d_in[0];
    const int*   ei      = (const int*)d_in[1];
    const float* W1_rel  = (const float*)d_in[2];
    const float* b1      = (const float*)d_in[3];
    const float* W1_root = (const float*)d_in[4];
    const float* W2_rel  = (const float*)d_in[5];
    const float* b2      = (const float*)d_in[6];
    const float* W2_root = (const float*)d_in[7];
    float* out = (float*)d_out;

    const int N = in_sizes[0] / F_IN;       // 50000
    const int E = in_sizes[1] / 2;          // 800000
    const int slice_size = ((N + 2047) / 2048) * 256;   // 6400

    // Workspace (~42 MB):
    char* ws = (char*)d_ws;
    size_t p = 0;
    unsigned short* xb   = (unsigned short*)(ws + p); p += (size_t)N_NODES * F_IN * 2;
    unsigned short* h    = (unsigned short*)(ws + p); p += (size_t)N_NODES * HIDDEN * 2;
    unsigned short* t    = (unsigned short*)(ws + p); p += (size_t)N_NODES * OUT_F * 2;
    unsigned short* W1b  = (unsigned short*)(ws + p); p += (size_t)128 * 192 * 2;
    unsigned short* W2rb = (unsigned short*)(ws + p); p += (size_t)64 * 128 * 2;
    unsigned short* W2sb = (unsigned short*)(ws + p); p += (size_t)64 * 128 * 2;
    int* deg = (int*)(ws + p);  p += (size_t)N_NODES * 4;
    int* csr = (int*)(ws + p);  p += (size_t)N_NODES * DCAP * 4;   // 12.8 MB

    // ---- 1: zero deg ----
    hipMemsetAsync(deg, 0, (size_t)N * 4, stream);

    // ---- 2: fused setup + place ----
    {
        int total8 = N * F_IN / 8;          // 600000
        int SB = (total8 + 255) / 256;      // 2344 setup blocks
        int E4 = E >> 2;
        int bps = (E4 + 1 + 255) / 256;     // 782
        int PB = bps * 8;                   // 6256 place blocks
        setup_place_kernel<<<SB + PB, 256, 0, stream>>>(
            x, W1_rel, W1_root, W2_rel, W2_root, ei,
            xb, W1b, W2rb, W2sb, deg, csr, SB, total8, E, slice_size);
    }

    const int tiles32 = (N + 31) / 32;       // 1563

    // ---- 3: gather1 + gemm1 + gemm2 ----
    mega1_kernel<<<tiles32, 256, 0, stream>>>(xb, W1b, W2rb, b1, deg, csr, h, t, N);

    // ---- 4: gather2 + gemm3 ----
    gemm3_fused<<<tiles32, 256, 0, stream>>>(h, t, W2sb, b2, deg, csr, out, N);
}